// Round 12
// baseline (866.764 us; speedup 1.0000x reference)
//
#include <hip/hip_runtime.h>
#include <hip/hip_bf16.h>
#include <stdint.h>

// Problem constants
#define SEQ   2048
#define NHEAD 32
#define HDIM  128
#define DMODEL 4096
#define MTOT  4096          // B*S
#define RSCALE 0.08838834764831845f  // 1/sqrt(128)

typedef __hip_bfloat16 bf16_t;
typedef __attribute__((ext_vector_type(8))) short short8v;
typedef __attribute__((ext_vector_type(4))) short short4v;
typedef __attribute__((ext_vector_type(4))) float f32x4;
typedef __attribute__((ext_vector_type(2))) float f32x2;

typedef __attribute__((address_space(3))) void lds_void;
typedef __attribute__((address_space(1))) void gbl_void;
#define TO_LDS(p) ((lds_void*)(uint32_t)(uintptr_t)(p))
#define TO_GBL(p) ((gbl_void*)(uintptr_t)(p))
#define ASYNC_CP16(g, l) __builtin_amdgcn_global_load_lds(TO_GBL(g), TO_LDS(l), 16, 0, 0)

__device__ __forceinline__ float bf2f(short u) {
  union { uint32_t i; float f; } x; x.i = ((uint32_t)(uint16_t)u) << 16; return x.f;
}

#define VMW_(N) asm volatile("s_waitcnt vmcnt(" #N ")" ::: "memory")
#define VMW(N) VMW_(N)
#define SB0 __builtin_amdgcn_sched_barrier(0)

// ---------------------------------------------------------------- cast f32->bf16 (batched x,wq,wk,wv)
__global__ __launch_bounds__(256) void cast4_f32_to_bf16(const float* __restrict__ s0,
                                                         const float* __restrict__ s1,
                                                         const float* __restrict__ s2,
                                                         const float* __restrict__ s3,
                                                         bf16_t* __restrict__ out) {
  const int w = blockIdx.y;
  const float* in = (w == 0) ? s0 : ((w == 1) ? s1 : ((w == 2) ? s2 : s3));
  bf16_t* o = out + (size_t)w * 16777216u;
  size_t i = (size_t)blockIdx.x * 256 + threadIdx.x;
  const f32x4* p = (const f32x4*)in + i * 2;
  f32x4 a = p[0], b = p[1];
  __align__(16) bf16_t tmp[8];
#pragma unroll
  for (int j = 0; j < 4; ++j) tmp[j]     = __float2bfloat16(a[j]);
#pragma unroll
  for (int j = 0; j < 4; ++j) tmp[4 + j] = __float2bfloat16(b[j]);
  *(short8v*)(o + i * 8) = *(const short8v*)tmp;
}

// ---------------------------------------------------------------- NT GEMM: C = A @ B^T  (flatmm-lite)
// 256x256 tile, BK=64, 8 waves as 4M x 2N (wave tile 64 x 128).
// A-frags loaded DIRECT global->VGPR (contiguous 16B per lane, reg dbuf aA/aB).
// Only B staged in LDS (2 x 32KB slots, XOR-swizzled rows).
// Per K-tile: stage B(T+1) [4 gload_lds] + LDA(T+1) [8 dwordx4] + 16 ds_read
// + 64 MFMA + vmcnt(8) [drains the 4 stage loads, keeps 8 A-loads in flight]
// + one barrier. Compiler auto-counts A-load vmcnt and ds_read lgkm waits.
#define STAGE_BT(slot_, X)                                                     \
  { const int tr_ = tid >> 3, c_ = tid & 7;                                    \
    _Pragma("unroll")                                                          \
    for (int i_ = 0; i_ < 4; ++i_) {                                           \
      const int row_ = i_ * 64 + tr_;                                          \
      const int cg_ = c_ ^ (row_ & 7);                                         \
      ASYNC_CP16(gB0 + (size_t)row_ * 4096 + (size_t)(X) * 64 + cg_ * 8,       \
                 ldsc + (slot_) * 32768 + row_ * 128 + c_ * 16); } }

#define LDA(AR, X)                                                             \
  _Pragma("unroll") for (int m_ = 0; m_ < 4; ++m_)                             \
    _Pragma("unroll") for (int kk_ = 0; kk_ < 2; ++kk_)                        \
      AR[m_][kk_] = *(const short8v*)(gA0 + (size_t)m_ * 65536 +               \
                                      (size_t)(X) * 64 + kk_ * 32 + g * 8);

#define GTILE(TT, AC, AN, DOSTG)                                               \
  {                                                                            \
    const int slot_c = (TT) & 1;                                               \
    if (DOSTG) {                                                               \
      STAGE_BT(slot_c ^ 1, (TT) + 1);                                          \
      LDA(AN, (TT) + 1);                                                       \
    }                                                                          \
    __builtin_amdgcn_s_setprio(1);                                             \
    _Pragma("unroll") for (int n = 0; n < 8; ++n) {                            \
      const char* bp = ldsc + slot_c * 32768 + bRow + n * 2048;                \
      short8v b0 = *(const short8v*)(bp + cx0);                                \
      short8v b1 = *(const short8v*)(bp + cx1);                                \
      _Pragma("unroll") for (int m = 0; m < 4; ++m) {                          \
        acc[m][n] = __builtin_amdgcn_mfma_f32_16x16x32_bf16(AC[m][0], b0, acc[m][n], 0, 0, 0); \
        acc[m][n] = __builtin_amdgcn_mfma_f32_16x16x32_bf16(AC[m][1], b1, acc[m][n], 0, 0, 0); \
      }                                                                        \
    }                                                                          \
    __builtin_amdgcn_s_setprio(0);                                             \
    if (DOSTG) {                                                               \
      VMW(8);                                                                  \
      __builtin_amdgcn_s_barrier();                                            \
      SB0;                                                                     \
    }                                                                          \
  }

template <int MODE>   // 0: f32 C out; 1: fused qkv epilogue
__global__ __launch_bounds__(512, 2) void gemm_nt(const bf16_t* __restrict__ A,
                                                  const bf16_t* __restrict__ B0,
                                                  const bf16_t* __restrict__ B1,
                                                  const bf16_t* __restrict__ B2,
                                                  void* __restrict__ out0,
                                                  bf16_t* __restrict__ out1,
                                                  bf16_t* __restrict__ out2,
                                                  const float* __restrict__ freqs) {
  __shared__ __align__(16) char ldsbuf[65536];    // 2 slots x B(256x64 bf16)
  char* ldsc = ldsbuf;
  const int z = blockIdx.z;
  const bf16_t* __restrict__ Bm = (z == 0) ? B0 : (z == 1 ? B1 : B2);
  const int tid = threadIdx.x;
  const int wave = tid >> 6, lane = tid & 63;
  // XCD swizzle: each XCD owns 2 bm x 16 bn
  const int bid = blockIdx.x;                 // 0..255
  const int xcd = bid & 7, idx = bid >> 3;    // idx 0..31
  const int bm = xcd * 2 + (idx >> 4);        // 0..15
  const int bn = idx & 15;                    // 0..15
  const int wr = wave >> 1, wc = wave & 1;    // 4M x 2N wave grid
  const int r = lane & 15, g = lane >> 4;

  f32x4 acc[4][8] = {};

  const bf16_t* gA0 = A + ((size_t)(bm * 256 + wr * 64 + r)) * 4096;
  const bf16_t* gB0 = Bm + (size_t)bn * 256 * 4096;

  // B ds_read address pieces (swizzle: LDS chunk c holds global chunk c^(row&7))
  const int swz = r & 7;
  const int cx0 = (g ^ swz) << 4;               // kk=0
  const int cx1 = ((4 + g) ^ swz) << 4;         // kk=1
  const int bRow = (wc * 128 + r) * 128;        // + n*2048

  short8v aA[4][2], aB[4][2];

  // prologue: stage B(0), load A(0); vmcnt(8) drains the 4 stage loads
  STAGE_BT(0, 0);
  LDA(aA, 0);
  VMW(8);
  __builtin_amdgcn_s_barrier();
  SB0;

  for (int T = 0; T < 62; T += 2) {
    GTILE(T, aA, aB, 1);
    GTILE(T + 1, aB, aA, 1);
  }
  GTILE(62, aA, aB, 1);
  GTILE(63, aB, aA, 0);

  const int row0 = bm * 256 + wr * 64 + g * 4;    // + m*16 + j
  const int col0 = bn * 256 + wc * 128;           // + n*16 + r

  if (MODE == 0) {
    float* C = (float*)out0;
#pragma unroll
    for (int m = 0; m < 4; ++m)
#pragma unroll
      for (int n = 0; n < 8; ++n)
#pragma unroll
        for (int j = 0; j < 4; ++j)
          C[(size_t)(row0 + m * 16 + j) * 4096 + col0 + n * 16 + r] = acc[m][n][j];
  } else if (z == 2) {
    // V transpose: vt[(b*32+h)*128 + d][s], 4 consecutive s per 8B store
    bf16_t* VT = out2;
#pragma unroll
    for (int m = 0; m < 4; ++m) {
      const int row = row0 + m * 16;              // j = 0..3 -> s consecutive
      const int b = row >> 11, s = row & 2047;
#pragma unroll
      for (int n = 0; n < 8; ++n) {
        const int col = col0 + n * 16 + r;
        const int h = col >> 7, d = col & 127;
        __align__(8) bf16_t tp[4];
#pragma unroll
        for (int j = 0; j < 4; ++j) tp[j] = __float2bfloat16(acc[m][n][j]);
        *(short4v*)&VT[((size_t)(b * 32 + h) * 128 + d) * 2048 + s] = *(const short4v*)tp;
      }
    }
  } else if (z == 0) {
    // Q: plain relayout to [bh][s][d]; RoPE applied in attn at Q-load.
    bf16_t* dst = (bf16_t*)out0;
#pragma unroll
    for (int m = 0; m < 4; ++m)
#pragma unroll
      for (int j = 0; j < 4; ++j) {
        const int row = row0 + m * 16 + j;
        const int b = row >> 11, s = row & 2047;
#pragma unroll
        for (int n = 0; n < 8; ++n) {
          const int col = col0 + n * 16 + r;
          const int h = col >> 7, d = col & 127;
          dst[((size_t)(b * 32 + h) * 2048 + s) * 128 + d] = __float2bfloat16(acc[m][n][j]);
        }
      }
  } else {
    // K: RoPE fused (partner in lane r^1; d-parity == lane-parity), [bh][s][d].
    bf16_t* dst = out1;
    const float sgn = (r & 1) ? 1.0f : -1.0f;
#pragma unroll
    for (int m = 0; m < 4; ++m)
#pragma unroll
      for (int j = 0; j < 4; ++j) {
        const int row = row0 + m * 16 + j;
        const int b = row >> 11, s = row & 2047;
#pragma unroll
        for (int n = 0; n < 8; ++n) {
          const int col = col0 + n * 16 + r;
          const int h = col >> 7, d = col & 127;
          const float self = acc[m][n][j];
          const float part = __shfl_xor(self, 1, 64);
          const float* fp = freqs + (size_t)s * 128 + (d >> 1) * 2;
          const float frv = fp[0];
          const float fiv = fp[1] * sgn;
          dst[((size_t)(b * 32 + h) * 2048 + s) * 128 + d] =
              __float2bfloat16(self * frv + part * fiv);
        }
      }
  }
}

// ---------------------------------------------------------------- flash attention (+ wo cast side-blocks)
// Blocks 0..1023: 8 warps x 16 q-rows, 2-buffer K/V dbuf, swizzled P, Q roped
// in-register. Blocks 1024..1535: cast wo f32->bf16 (overlaps attn; HBM idle).
__global__ __launch_bounds__(512) void attn_kernel(const bf16_t* __restrict__ qrot,
                                                   const bf16_t* __restrict__ krot,
                                                   const bf16_t* __restrict__ vt,
                                                   const float* __restrict__ freqs,
                                                   bf16_t* __restrict__ att,
                                                   const float* __restrict__ wo_src,
                                                   bf16_t* __restrict__ wo_dst) {
  __shared__ bf16_t Kls[2][64 * 128];   // 32 KB
  __shared__ bf16_t Vls[2][128 * 64];   // 32 KB
  __shared__ bf16_t Pls[8][16 * 64];    // 16 KB, XOR-swizzled

  if (blockIdx.x >= 1024) {             // wo cast: 512 blocks x 8 passes x 8 elems
    const int cb = blockIdx.x - 1024;
    const int tid = threadIdx.x;
#pragma unroll
    for (int p = 0; p < 8; ++p) {
      size_t i = ((size_t)p * 512 + cb) * 512 + tid;
      const f32x4* pp = (const f32x4*)wo_src + i * 2;
      f32x4 a = pp[0], b = pp[1];
      __align__(16) bf16_t tmp[8];
#pragma unroll
      for (int j = 0; j < 4; ++j) tmp[j]     = __float2bfloat16(a[j]);
#pragma unroll
      for (int j = 0; j < 4; ++j) tmp[4 + j] = __float2bfloat16(b[j]);
      *(short8v*)(wo_dst + i * 8) = *(const short8v*)tmp;
    }
    return;
  }

  const int lid  = blockIdx.x;             // 0..1023
  const int xcd  = lid & 7;
  const int kk_  = lid >> 3;               // 0..127
  const int bh   = xcd + 8 * ((kk_ >> 4) & 7);
  const int qidx = 15 - (kk_ & 15);        // longest blocks dispatched first
  const int warp = threadIdx.x >> 6;
  const int lane = threadIdx.x & 63;
  const int r = lane & 15, g = lane >> 4;

  const bf16_t* __restrict__ Q  = qrot + (size_t)bh * 2048 * 128;
  const bf16_t* __restrict__ Kp = krot + (size_t)bh * 2048 * 128;
  const bf16_t* __restrict__ Vt = vt   + (size_t)bh * 128 * 2048;
  char* __restrict__ Pb = (char*)&Pls[warp][0];

  const int qB = qidx * 128 + warp * 16;
  const int ntiles = 2 * qidx + 2;
  const int psw = (r & 7) << 4;            // P swizzle

  // Q fragments: load raw, apply RoPE + RSCALE in-register (once per block).
  short8v qf[4];
  {
    const int s = qB + r;
    const float* fbase = freqs + (size_t)s * 128;
#pragma unroll
    for (int kk = 0; kk < 4; ++kk) {
      short8v qraw = *(const short8v*)&Q[(size_t)s * 128 + kk * 32 + g * 8];
      __align__(16) bf16_t qt[8];
#pragma unroll
      for (int i = 0; i < 4; ++i) {
        const int p = kk * 16 + g * 4 + i;
        f32x2 cs = *(const f32x2*)(fbase + p * 2);
        const float a = bf2f(qraw[2 * i]), b = bf2f(qraw[2 * i + 1]);
        qt[2 * i]     = __float2bfloat16((a * cs[0] - b * cs[1]) * RSCALE);
        qt[2 * i + 1] = __float2bfloat16((a * cs[1] + b * cs[0]) * RSCALE);
      }
      qf[kk] = *(const short8v*)qt;
    }
  }

  float l = 0.f;
  f32x4 o[8];
#pragma unroll
  for (int n2 = 0; n2 < 8; ++n2) o[n2] = f32x4{0.f, 0.f, 0.f, 0.f};

  const int rA = lane >> 4, cA = lane & 15;
  const int rB = lane >> 3, cB = lane & 7;
  const int swz = (r & 7) << 4;

  auto STG = [&](int kb_, int buf) {
#pragma unroll
    for (int i = 0; i < 2; ++i) {
      const int krow = warp * 8 + i * 4 + rA;
      const int kcol = 8 * (cA ^ (krow & 7));
      ASYNC_CP16(Kp + (size_t)(kb_ + krow) * 128 + kcol,
                 (char*)&Kls[buf][0] + (size_t)(krow * 128 + cA * 8) * 2);
    }
#pragma unroll
    for (int i = 0; i < 2; ++i) {
      const int vrow = warp * 16 + i * 8 + rB;
      const int vcol = 8 * (cB ^ rB);
      ASYNC_CP16(Vt + (size_t)vrow * 2048 + kb_ + vcol,
                 (char*)&Vls[buf][0] + (size_t)(vrow * 64 + cB * 8) * 2);
    }
  };

  STG(0, 0);
  VMW(0);
  __builtin_amdgcn_s_barrier();
  int cur = 0;
  for (int t = 0; t < ntiles; ++t) {
    const int kb = t * 64;
    if (t + 1 < ntiles) STG(kb + 64, cur ^ 1);

    if (kb <= qB + 15) {
      const char* Kc = (const char*)&Kls[cur][0];
      const char* Vc = (const char*)&Vls[cur][0];
      f32x4 sacc[4];
#pragma unroll
      for (int n = 0; n < 4; ++n) sacc[n] = f32x4{0.f, 0.f, 0.f, 0.f};
#pragma unroll
      for (int n = 0; n < 4; ++n)
#pragma unroll
        for (int kk = 0; kk < 4; ++kk) {
          short8v kf = *(const short8v*)(Kc + (n * 16 + r) * 256 + ((kk * 64 + g * 16) ^ swz));
          sacc[n] = __builtin_amdgcn_mfma_f32_16x16x32_bf16(kf, qf[kk], sacc[n], 0, 0, 0);
        }

      float p[16];
#pragma unroll
      for (int n = 0; n < 4; ++n)
#pragma unroll
        for (int j = 0; j < 4; ++j)
          p[n * 4 + j] = __expf(sacc[n][j]);

      if (kb + 63 > qB) {
        const int qa = qB + r;
#pragma unroll
        for (int n = 0; n < 4; ++n)
#pragma unroll
          for (int j = 0; j < 4; ++j)
            if (kb + n * 16 + g * 4 + j > qa) p[n * 4 + j] = 0.f;
      }

      {
        float ts[8];
#pragma unroll
        for (int i = 0; i < 8; ++i) ts[i] = p[i] + p[i + 8];
#pragma unroll
        for (int i = 0; i < 4; ++i) ts[i] += ts[i + 4];
        float rs = (ts[0] + ts[1]) + (ts[2] + ts[3]);
        rs += __shfl_xor(rs, 16, 64);
        rs += __shfl_xor(rs, 32, 64);
        l += rs;
      }

      // stage P, swizzled: raw byte = r*128 + n*32 + g*8, XOR (r&7)<<4
#pragma unroll
      for (int n = 0; n < 4; ++n) {
        __align__(8) bf16_t tp[4];
#pragma unroll
        for (int j = 0; j < 4; ++j) tp[j] = __float2bfloat16(p[n * 4 + j]);
        *(short4v*)(Pb + r * 128 + ((n * 32 + g * 8) ^ psw)) = *(const short4v*)tp;
      }

#pragma unroll
      for (int kk2 = 0; kk2 < 2; ++kk2) {
        short8v pf = *(const short8v*)(Pb + r * 128 + ((kk2 * 64 + g * 16) ^ psw));
#pragma unroll
        for (int n2 = 0; n2 < 8; ++n2) {
          short8v vf = *(const short8v*)(Vc + (n2 * 16 + r) * 128 + ((kk2 * 64 + g * 16) ^ swz));
          o[n2] = __builtin_amdgcn_mfma_f32_16x16x32_bf16(pf, vf, o[n2], 0, 0, 0);
        }
      }
    }

    if (t + 1 < ntiles) {
      VMW(0);                       // my t+1 loads landed during compute(t)
      __builtin_amdgcn_s_barrier(); // publish all warps' loads; WAR fence
    }
    cur ^= 1;
  }

  float lq[4];
#pragma unroll
  for (int j = 0; j < 4; ++j) lq[j] = 1.0f / __shfl(l, g * 4 + j, 64);
  const int b = bh >> 5, h = bh & 31;
#pragma unroll
  for (int n2 = 0; n2 < 8; ++n2)
#pragma unroll
    for (int j = 0; j < 4; ++j)
      att[((size_t)(b * 2048 + qB + g * 4 + j)) * 4096 + h * 128 + n2 * 16 + r] =
          __float2bfloat16(o[n2][j] * lq[j]);
}

// ---------------------------------------------------------------- launch
extern "C" void kernel_launch(void* const* d_in, const int* in_sizes, int n_in,
                              void* d_out, int out_size, void* d_ws, size_t ws_size,
                              hipStream_t stream) {
  (void)in_sizes; (void)n_in; (void)out_size; (void)ws_size;
  const float* x  = (const float*)d_in[0];
  const float* fr = (const float*)d_in[1];
  const float* wq = (const float*)d_in[3];
  const float* wk = (const float*)d_in[4];
  const float* wv = (const float*)d_in[5];
  const float* wo = (const float*)d_in[6];

  char* ws = (char*)d_ws;
  const size_t MB32 = 33554432;
  bf16_t* xb   = (bf16_t*)(ws + 0 * MB32);   // later: attb
  bf16_t* wqb  = (bf16_t*)(ws + 1 * MB32);   // later: wob
  bf16_t* wkb  = (bf16_t*)(ws + 2 * MB32);
  bf16_t* wvb  = (bf16_t*)(ws + 3 * MB32);
  bf16_t* qrot = (bf16_t*)(ws + 4 * MB32);   // raw Q (relayout only)
  bf16_t* krot = (bf16_t*)(ws + 5 * MB32);
  bf16_t* vtp  = (bf16_t*)(ws + 6 * MB32);

  cast4_f32_to_bf16<<<dim3(8192, 4), 256, 0, stream>>>(x, wq, wk, wv, xb);

  // qkv projections; z=0 relayout, z=1 rope, z=2 transpose
  gemm_nt<1><<<dim3(256, 1, 3), 512, 0, stream>>>(xb, wqb, wkb, wvb,
                                                  (void*)qrot, krot, vtp, fr);

  bf16_t* wob  = wqb;
  bf16_t* attb = xb;

  // attn + concurrent wo cast (blocks >= 1024)
  attn_kernel<<<1536, 512, 0, stream>>>(qrot, krot, vtp, fr, attb, wo, wob);

  gemm_nt<0><<<dim3(256, 1, 1), 512, 0, stream>>>(attb, wob, wob, wob,
                                                  d_out, nullptr, nullptr, nullptr);
}

// Round 13
// 639.357 us; speedup vs baseline: 1.3557x; 1.3557x over previous
//
#include <hip/hip_runtime.h>
#include <hip/hip_bf16.h>
#include <stdint.h>

// Problem constants
#define SEQ   2048
#define NHEAD 32
#define HDIM  128
#define DMODEL 4096
#define MTOT  4096          // B*S
#define RSCALE 0.08838834764831845f  // 1/sqrt(128)

typedef __hip_bfloat16 bf16_t;
typedef __attribute__((ext_vector_type(8))) short short8v;
typedef __attribute__((ext_vector_type(4))) short short4v;
typedef __attribute__((ext_vector_type(4))) float f32x4;
typedef __attribute__((ext_vector_type(2))) float f32x2;

typedef __attribute__((address_space(3))) void lds_void;
typedef __attribute__((address_space(1))) void gbl_void;
#define TO_LDS(p) ((lds_void*)(uint32_t)(uintptr_t)(p))
#define TO_GBL(p) ((gbl_void*)(uintptr_t)(p))
#define ASYNC_CP16(g, l) __builtin_amdgcn_global_load_lds(TO_GBL(g), TO_LDS(l), 16, 0, 0)

__device__ __forceinline__ float bf2f(short u) {
  union { uint32_t i; float f; } x; x.i = ((uint32_t)(uint16_t)u) << 16; return x.f;
}

#define VMW_(N) asm volatile("s_waitcnt vmcnt(" #N ")" ::: "memory")
#define VMW(N) VMW_(N)
#define SB0 __builtin_amdgcn_sched_barrier(0)
#define LGKM0 asm volatile("s_waitcnt lgkmcnt(0)" ::: "memory")
#define LGKM8 asm volatile("s_waitcnt lgkmcnt(8)" ::: "memory")

// ---------------------------------------------------------------- cast f32->bf16 (batched x,wq,wk,wv)
__global__ __launch_bounds__(256) void cast4_f32_to_bf16(const float* __restrict__ s0,
                                                         const float* __restrict__ s1,
                                                         const float* __restrict__ s2,
                                                         const float* __restrict__ s3,
                                                         bf16_t* __restrict__ out) {
  const int w = blockIdx.y;
  const float* in = (w == 0) ? s0 : ((w == 1) ? s1 : ((w == 2) ? s2 : s3));
  bf16_t* o = out + (size_t)w * 16777216u;
  size_t i = (size_t)blockIdx.x * 256 + threadIdx.x;
  const f32x4* p = (const f32x4*)in + i * 2;
  f32x4 a = p[0], b = p[1];
  __align__(16) bf16_t tmp[8];
#pragma unroll
  for (int j = 0; j < 4; ++j) tmp[j]     = __float2bfloat16(a[j]);
#pragma unroll
  for (int j = 0; j < 4; ++j) tmp[4 + j] = __float2bfloat16(b[j]);
  *(short8v*)(o + i * 8) = *(const short8v*)tmp;
}

// ---------------------------------------------------------------- NT GEMM: C = A @ B^T
// 256x256 tile, BK=64, 8 waves (2M x 4N), 2-slot LDS dbuf, XOR-swizzled rows.
// m201-style 8-phase schedule (4 phases per K-tile, 2 tiles per iteration):
// each phase: {ds-read subtile || stage ONE half-tile} -> barrier -> lgkm(0)
// -> 16 MFMA (setprio) -> barrier. vmcnt(6) ONLY at phases 4/8 (once/K-tile):
// queue at that point = 14 loads, drains 8 (= entire next tile), leaves 6
// (3 half-tiles of tile t+2 in flight). End-of-phase barriers make every
// LDS overwrite WAR-safe (region read-complete >= 1 barrier earlier).
#define STAGE_A(mh_, X)                                                        \
  { const int tr_ = tid >> 3, c_ = tid & 7;                                    \
    _Pragma("unroll")                                                          \
    for (int i_ = 0; i_ < 2; ++i_) {                                           \
      const int row_ = (mh_) * 64 + i_ * 128 + tr_;                            \
      const int cg_ = c_ ^ (row_ & 7);                                         \
      ASYNC_CP16(gA0 + (size_t)row_ * 4096 + (size_t)(X) * 64 + cg_ * 8,       \
                 ldsc + (((X) & 1) << 16) + row_ * 128 + c_ * 16); } }

#define STAGE_B(nh_, X)                                                        \
  { const int tr_ = tid >> 3, c_ = tid & 7;                                    \
    _Pragma("unroll")                                                          \
    for (int i_ = 0; i_ < 2; ++i_) {                                           \
      const int row_ = i_ * 128 + (tr_ >> 5) * 64 + (nh_) * 32 + (tr_ & 31);   \
      const int cg_ = c_ ^ (row_ & 7);                                         \
      ASYNC_CP16(gB0 + (size_t)row_ * 4096 + (size_t)(X) * 64 + cg_ * 8,       \
                 ldsc + (((X) & 1) << 16) + 32768 + row_ * 128 + c_ * 16); } }

#define RD_A(AR, SL, MH)                                                       \
  _Pragma("unroll") for (int m_ = 0; m_ < 4; ++m_) {                           \
    AR[m_][0] = *(const short8v*)(ldsc + (SL) + aRow + (MH) * 8192 + m_ * 2048 + cx0); \
    AR[m_][1] = *(const short8v*)(ldsc + (SL) + aRow + (MH) * 8192 + m_ * 2048 + cx1); }

#define RD_B(BR, SL, NH)                                                       \
  _Pragma("unroll") for (int n_ = 0; n_ < 2; ++n_) {                           \
    BR[n_][0] = *(const short8v*)(ldsc + (SL) + bRow + (NH) * 4096 + n_ * 2048 + cx0); \
    BR[n_][1] = *(const short8v*)(ldsc + (SL) + bRow + (NH) * 4096 + n_ * 2048 + cx1); }

#define MFMA16(AR, BR, MH, NH)                                                 \
  __builtin_amdgcn_s_setprio(1);                                               \
  _Pragma("unroll") for (int m_ = 0; m_ < 4; ++m_)                             \
    _Pragma("unroll") for (int n_ = 0; n_ < 2; ++n_) {                         \
      acc[(MH)*4+m_][(NH)*2+n_] = __builtin_amdgcn_mfma_f32_16x16x32_bf16(     \
          AR[m_][0], BR[n_][0], acc[(MH)*4+m_][(NH)*2+n_], 0, 0, 0);           \
      acc[(MH)*4+m_][(NH)*2+n_] = __builtin_amdgcn_mfma_f32_16x16x32_bf16(     \
          AR[m_][1], BR[n_][1], acc[(MH)*4+m_][(NH)*2+n_], 0, 0, 0); }         \
  __builtin_amdgcn_s_setprio(0);

#define BAR __builtin_amdgcn_s_barrier()

#define KTILE(T, SB1_, SA0_, SB0_, SA1_, VMC)                                  \
  {                                                                            \
    const int sl = ((T) & 1) << 16;                                            \
    /* ph1: (0,0) */                                                           \
    RD_A(a0, sl, 0); RD_B(b0, sl, 0);                                          \
    if (SB1_) STAGE_B(1, (T) + 1);                                             \
    LGKM8;                                                                     \
    BAR; LGKM0; SB0;                                                           \
    MFMA16(a0, b0, 0, 0);                                                      \
    BAR;                                                                       \
    /* ph2: (1,0) */                                                           \
    RD_A(a1, sl, 1);                                                           \
    if (SA0_) STAGE_A(0, (T) + 2);                                             \
    BAR; LGKM0; SB0;                                                           \
    MFMA16(a1, b0, 1, 0);                                                      \
    BAR;                                                                       \
    /* ph3: (1,1) */                                                           \
    RD_B(b1, sl, 1);                                                           \
    if (SB0_) STAGE_B(0, (T) + 2);                                             \
    BAR; LGKM0; SB0;                                                           \
    MFMA16(a1, b1, 1, 1);                                                      \
    BAR;                                                                       \
    /* ph4: (0,1) — regs only; counted vmcnt once per K-tile */                \
    if (SA1_) STAGE_A(1, (T) + 2);                                             \
    VMC;                                                                       \
    BAR;                                                                       \
    MFMA16(a0, b1, 0, 1);                                                      \
    BAR;                                                                       \
  }

template <int MODE>   // 0: f32 C out; 1: fused qkv epilogue
__global__ __launch_bounds__(512, 2) void gemm_nt(const bf16_t* __restrict__ A,
                                                  const bf16_t* __restrict__ B0,
                                                  const bf16_t* __restrict__ B1,
                                                  const bf16_t* __restrict__ B2,
                                                  void* __restrict__ out0,
                                                  bf16_t* __restrict__ out1,
                                                  bf16_t* __restrict__ out2,
                                                  const float* __restrict__ freqs) {
  __shared__ __align__(16) char ldsbuf[131072];   // 2 slots x (A 32KB + B 32KB)
  char* ldsc = ldsbuf;
  const int z = blockIdx.z;
  const bf16_t* __restrict__ Bm = (z == 0) ? B0 : (z == 1 ? B1 : B2);
  const int tid = threadIdx.x;
  const int wave = tid >> 6, lane = tid & 63;
  // XCD swizzle: each XCD owns 2 bm x 16 bn
  const int bid = blockIdx.x;                 // 0..255
  const int xcd = bid & 7, idx = bid >> 3;    // idx 0..31
  const int bm = xcd * 2 + (idx >> 4);        // 0..15
  const int bn = idx & 15;                    // 0..15
  const int wr = wave >> 2, wc = wave & 3;    // 2 x 4 wave grid
  const int r = lane & 15, g = lane >> 4;

  f32x4 acc[8][4] = {};

  const bf16_t* gA0 = A  + (size_t)bm * 256 * 4096;
  const bf16_t* gB0 = Bm + (size_t)bn * 256 * 4096;

  // ds_read address pieces
  const int swz = r & 7;
  const int cx0 = (g ^ swz) << 4;             // kk=0 chunk byte offset
  const int cx1 = ((4 + g) ^ swz) << 4;       // kk=1
  const int aRow = (wr * 128 + r) * 128;      // + mh*8192 + m*2048
  const int bRow = 32768 + (wc * 64 + r) * 128; // + nh*4096 + n*2048

  short8v a0[4][2], a1[4][2], b0[2][2], b1[2][2];

  // prologue: tile0 (A0,B0 first so VMW(4) drains exactly those), then
  // 3 half-tiles of tile1; VMW(6) leaves exactly those 3 in flight.
  STAGE_A(0, 0);
  STAGE_B(0, 0);
  STAGE_A(1, 0);
  STAGE_B(1, 0);
  VMW(4);
  STAGE_A(0, 1);
  STAGE_B(0, 1);
  STAGE_A(1, 1);
  VMW(6);
  BAR;

  for (int it = 0; it < 31; ++it) {
    const int T0 = 2 * it;
    KTILE(T0,     1, 1, 1, 1, VMW(6));
    KTILE(T0 + 1, 1, 1, 1, 1, VMW(6));
  }
  KTILE(62, 1, 0, 0, 0, VMW(0));
  KTILE(63, 0, 0, 0, 0, (void)0);

  const int row0 = bm * 256 + wr * 128 + g * 4;   // + m*16 + j
  const int col0 = bn * 256 + wc * 64;            // + n*16 + r

  if (MODE == 0) {
    float* C = (float*)out0;
#pragma unroll
    for (int m = 0; m < 8; ++m)
#pragma unroll
      for (int n = 0; n < 4; ++n)
#pragma unroll
        for (int j = 0; j < 4; ++j)
          C[(size_t)(row0 + m * 16 + j) * 4096 + col0 + n * 16 + r] = acc[m][n][j];
  } else if (z == 2) {
    // V transpose: vt[(b*32+h)*128 + d][s], 4 consecutive s per 8B store
    bf16_t* VT = out2;
#pragma unroll
    for (int m = 0; m < 8; ++m) {
      const int row = row0 + m * 16;            // j = 0..3 -> s consecutive
      const int b = row >> 11, s = row & 2047;
#pragma unroll
      for (int n = 0; n < 4; ++n) {
        const int col = col0 + n * 16 + r;
        const int h = col >> 7, d = col & 127;
        __align__(8) bf16_t tp[4];
#pragma unroll
        for (int j = 0; j < 4; ++j) tp[j] = __float2bfloat16(acc[m][n][j]);
        *(short4v*)&VT[((size_t)(b * 32 + h) * 128 + d) * 2048 + s] = *(const short4v*)tp;
      }
    }
  } else if (z == 0) {
    // Q: plain relayout to [bh][s][d]; RoPE applied in attn at Q-load.
    bf16_t* dst = (bf16_t*)out0;
#pragma unroll
    for (int m = 0; m < 8; ++m)
#pragma unroll
      for (int j = 0; j < 4; ++j) {
        const int row = row0 + m * 16 + j;
        const int b = row >> 11, s = row & 2047;
#pragma unroll
        for (int n = 0; n < 4; ++n) {
          const int col = col0 + n * 16 + r;
          const int h = col >> 7, d = col & 127;
          dst[((size_t)(b * 32 + h) * 2048 + s) * 128 + d] = __float2bfloat16(acc[m][n][j]);
        }
      }
  } else {
    // K: RoPE fused (partner in lane r^1; d-parity == lane-parity), [bh][s][d].
    bf16_t* dst = out1;
    const float sgn = (r & 1) ? 1.0f : -1.0f;
#pragma unroll
    for (int m = 0; m < 8; ++m)
#pragma unroll
      for (int j = 0; j < 4; ++j) {
        const int row = row0 + m * 16 + j;
        const int b = row >> 11, s = row & 2047;
#pragma unroll
        for (int n = 0; n < 4; ++n) {
          const int col = col0 + n * 16 + r;
          const int h = col >> 7, d = col & 127;
          const float self = acc[m][n][j];
          const float part = __shfl_xor(self, 1, 64);
          const float* fp = freqs + (size_t)s * 128 + (d >> 1) * 2;
          const float frv = fp[0];
          const float fiv = fp[1] * sgn;
          dst[((size_t)(b * 32 + h) * 2048 + s) * 128 + d] =
              __float2bfloat16(self * frv + part * fiv);
        }
      }
  }
}

// ---------------------------------------------------------------- flash attention (+ wo cast side-blocks)
// Blocks 0..1023: 8 warps x 16 q-rows, 2-buffer K/V dbuf, swizzled P, Q roped
// in-register. Blocks 1024..1535: cast wo f32->bf16 (overlaps attn; HBM idle).
__global__ __launch_bounds__(512) void attn_kernel(const bf16_t* __restrict__ qrot,
                                                   const bf16_t* __restrict__ krot,
                                                   const bf16_t* __restrict__ vt,
                                                   const float* __restrict__ freqs,
                                                   bf16_t* __restrict__ att,
                                                   const float* __restrict__ wo_src,
                                                   bf16_t* __restrict__ wo_dst) {
  __shared__ bf16_t Kls[2][64 * 128];   // 32 KB
  __shared__ bf16_t Vls[2][128 * 64];   // 32 KB
  __shared__ bf16_t Pls[8][16 * 64];    // 16 KB, XOR-swizzled

  if (blockIdx.x >= 1024) {             // wo cast: 512 blocks x 8 passes x 8 elems
    const int cb = blockIdx.x - 1024;
    const int tid = threadIdx.x;
#pragma unroll
    for (int p = 0; p < 8; ++p) {
      size_t i = ((size_t)p * 512 + cb) * 512 + tid;
      const f32x4* pp = (const f32x4*)wo_src + i * 2;
      f32x4 a = pp[0], b = pp[1];
      __align__(16) bf16_t tmp[8];
#pragma unroll
      for (int j = 0; j < 4; ++j) tmp[j]     = __float2bfloat16(a[j]);
#pragma unroll
      for (int j = 0; j < 4; ++j) tmp[4 + j] = __float2bfloat16(b[j]);
      *(short8v*)(wo_dst + i * 8) = *(const short8v*)tmp;
    }
    return;
  }

  const int lid  = blockIdx.x;             // 0..1023
  const int xcd  = lid & 7;
  const int kk_  = lid >> 3;               // 0..127
  const int bh   = xcd + 8 * ((kk_ >> 4) & 7);
  const int qidx = 15 - (kk_ & 15);        // longest blocks dispatched first
  const int warp = threadIdx.x >> 6;
  const int lane = threadIdx.x & 63;
  const int r = lane & 15, g = lane >> 4;

  const bf16_t* __restrict__ Q  = qrot + (size_t)bh * 2048 * 128;
  const bf16_t* __restrict__ Kp = krot + (size_t)bh * 2048 * 128;
  const bf16_t* __restrict__ Vt = vt   + (size_t)bh * 128 * 2048;
  char* __restrict__ Pb = (char*)&Pls[warp][0];

  const int qB = qidx * 128 + warp * 16;
  const int ntiles = 2 * qidx + 2;
  const int psw = (r & 7) << 4;            // P swizzle

  // Q fragments: load raw, apply RoPE + RSCALE in-register (once per block).
  short8v qf[4];
  {
    const int s = qB + r;
    const float* fbase = freqs + (size_t)s * 128;
#pragma unroll
    for (int kk = 0; kk < 4; ++kk) {
      short8v qraw = *(const short8v*)&Q[(size_t)s * 128 + kk * 32 + g * 8];
      __align__(16) bf16_t qt[8];
#pragma unroll
      for (int i = 0; i < 4; ++i) {
        const int p = kk * 16 + g * 4 + i;
        f32x2 cs = *(const f32x2*)(fbase + p * 2);
        const float a = bf2f(qraw[2 * i]), b = bf2f(qraw[2 * i + 1]);
        qt[2 * i]     = __float2bfloat16((a * cs[0] - b * cs[1]) * RSCALE);
        qt[2 * i + 1] = __float2bfloat16((a * cs[1] + b * cs[0]) * RSCALE);
      }
      qf[kk] = *(const short8v*)qt;
    }
  }

  float l = 0.f;
  f32x4 o[8];
#pragma unroll
  for (int n2 = 0; n2 < 8; ++n2) o[n2] = f32x4{0.f, 0.f, 0.f, 0.f};

  const int rA = lane >> 4, cA = lane & 15;
  const int rB = lane >> 3, cB = lane & 7;
  const int swz = (r & 7) << 4;

  auto STG = [&](int kb_, int buf) {
#pragma unroll
    for (int i = 0; i < 2; ++i) {
      const int krow = warp * 8 + i * 4 + rA;
      const int kcol = 8 * (cA ^ (krow & 7));
      ASYNC_CP16(Kp + (size_t)(kb_ + krow) * 128 + kcol,
                 (char*)&Kls[buf][0] + (size_t)(krow * 128 + cA * 8) * 2);
    }
#pragma unroll
    for (int i = 0; i < 2; ++i) {
      const int vrow = warp * 16 + i * 8 + rB;
      const int vcol = 8 * (cB ^ rB);
      ASYNC_CP16(Vt + (size_t)vrow * 2048 + kb_ + vcol,
                 (char*)&Vls[buf][0] + (size_t)(vrow * 64 + cB * 8) * 2);
    }
  };

  STG(0, 0);
  VMW(0);
  __builtin_amdgcn_s_barrier();
  int cur = 0;
  for (int t = 0; t < ntiles; ++t) {
    const int kb = t * 64;
    if (t + 1 < ntiles) STG(kb + 64, cur ^ 1);

    if (kb <= qB + 15) {
      const char* Kc = (const char*)&Kls[cur][0];
      const char* Vc = (const char*)&Vls[cur][0];
      f32x4 sacc[4];
#pragma unroll
      for (int n = 0; n < 4; ++n) sacc[n] = f32x4{0.f, 0.f, 0.f, 0.f};
#pragma unroll
      for (int n = 0; n < 4; ++n)
#pragma unroll
        for (int kk = 0; kk < 4; ++kk) {
          short8v kf = *(const short8v*)(Kc + (n * 16 + r) * 256 + ((kk * 64 + g * 16) ^ swz));
          sacc[n] = __builtin_amdgcn_mfma_f32_16x16x32_bf16(kf, qf[kk], sacc[n], 0, 0, 0);
        }

      float p[16];
#pragma unroll
      for (int n = 0; n < 4; ++n)
#pragma unroll
        for (int j = 0; j < 4; ++j)
          p[n * 4 + j] = __expf(sacc[n][j]);

      if (kb + 63 > qB) {
        const int qa = qB + r;
#pragma unroll
        for (int n = 0; n < 4; ++n)
#pragma unroll
          for (int j = 0; j < 4; ++j)
            if (kb + n * 16 + g * 4 + j > qa) p[n * 4 + j] = 0.f;
      }

      {
        float ts[8];
#pragma unroll
        for (int i = 0; i < 8; ++i) ts[i] = p[i] + p[i + 8];
#pragma unroll
        for (int i = 0; i < 4; ++i) ts[i] += ts[i + 4];
        float rs = (ts[0] + ts[1]) + (ts[2] + ts[3]);
        rs += __shfl_xor(rs, 16, 64);
        rs += __shfl_xor(rs, 32, 64);
        l += rs;
      }

      // stage P, swizzled: raw byte = r*128 + n*32 + g*8, XOR (r&7)<<4
#pragma unroll
      for (int n = 0; n < 4; ++n) {
        __align__(8) bf16_t tp[4];
#pragma unroll
        for (int j = 0; j < 4; ++j) tp[j] = __float2bfloat16(p[n * 4 + j]);
        *(short4v*)(Pb + r * 128 + ((n * 32 + g * 8) ^ psw)) = *(const short4v*)tp;
      }

#pragma unroll
      for (int kk2 = 0; kk2 < 2; ++kk2) {
        short8v pf = *(const short8v*)(Pb + r * 128 + ((kk2 * 64 + g * 16) ^ psw));
#pragma unroll
        for (int n2 = 0; n2 < 8; ++n2) {
          short8v vf = *(const short8v*)(Vc + (n2 * 16 + r) * 128 + ((kk2 * 64 + g * 16) ^ swz));
          o[n2] = __builtin_amdgcn_mfma_f32_16x16x32_bf16(pf, vf, o[n2], 0, 0, 0);
        }
      }
    }

    if (t + 1 < ntiles) {
      VMW(0);                       // my t+1 loads landed during compute(t)
      __builtin_amdgcn_s_barrier(); // publish all warps' loads; WAR fence
    }
    cur ^= 1;
  }

  float lq[4];
#pragma unroll
  for (int j = 0; j < 4; ++j) lq[j] = 1.0f / __shfl(l, g * 4 + j, 64);
  const int b = bh >> 5, h = bh & 31;
#pragma unroll
  for (int n2 = 0; n2 < 8; ++n2)
#pragma unroll
    for (int j = 0; j < 4; ++j)
      att[((size_t)(b * 2048 + qB + g * 4 + j)) * 4096 + h * 128 + n2 * 16 + r] =
          __float2bfloat16(o[n2][j] * lq[j]);
}

// ---------------------------------------------------------------- launch
extern "C" void kernel_launch(void* const* d_in, const int* in_sizes, int n_in,
                              void* d_out, int out_size, void* d_ws, size_t ws_size,
                              hipStream_t stream) {
  (void)in_sizes; (void)n_in; (void)out_size; (void)ws_size;
  const float* x  = (const float*)d_in[0];
  const float* fr = (const float*)d_in[1];
  const float* wq = (const float*)d_in[3];
  const float* wk = (const float*)d_in[4];
  const float* wv = (const float*)d_in[5];
  const float* wo = (const float*)d_in[6];

  char* ws = (char*)d_ws;
  const size_t MB32 = 33554432;
  bf16_t* xb   = (bf16_t*)(ws + 0 * MB32);   // later: attb
  bf16_t* wqb  = (bf16_t*)(ws + 1 * MB32);   // later: wob
  bf16_t* wkb  = (bf16_t*)(ws + 2 * MB32);
  bf16_t* wvb  = (bf16_t*)(ws + 3 * MB32);
  bf16_t* qrot = (bf16_t*)(ws + 4 * MB32);   // raw Q (relayout only)
  bf16_t* krot = (bf16_t*)(ws + 5 * MB32);
  bf16_t* vtp  = (bf16_t*)(ws + 6 * MB32);

  cast4_f32_to_bf16<<<dim3(8192, 4), 256, 0, stream>>>(x, wq, wk, wv, xb);

  // qkv projections; z=0 relayout, z=1 rope, z=2 transpose
  gemm_nt<1><<<dim3(256, 1, 3), 512, 0, stream>>>(xb, wqb, wkb, wvb,
                                                  (void*)qrot, krot, vtp, fr);

  bf16_t* wob  = wqb;
  bf16_t* attb = xb;

  // attn + concurrent wo cast (blocks >= 1024)
  attn_kernel<<<1536, 512, 0, stream>>>(qrot, krot, vtp, fr, attb, wo, wob);

  gemm_nt<0><<<dim3(256, 1, 1), 512, 0, stream>>>(attb, wob, wob, wob,
                                                  d_out, nullptr, nullptr, nullptr);
}

// Round 14
// 625.274 us; speedup vs baseline: 1.3862x; 1.0225x over previous
//
#include <hip/hip_runtime.h>
#include <hip/hip_bf16.h>
#include <stdint.h>

// Problem constants
#define SEQ   2048
#define NHEAD 32
#define HDIM  128
#define DMODEL 4096
#define MTOT  4096          // B*S
#define RSCALE 0.08838834764831845f  // 1/sqrt(128)

typedef __hip_bfloat16 bf16_t;
typedef __attribute__((ext_vector_type(8))) short short8v;
typedef __attribute__((ext_vector_type(4))) short short4v;
typedef __attribute__((ext_vector_type(4))) float f32x4;
typedef __attribute__((ext_vector_type(2))) float f32x2;

typedef __attribute__((address_space(3))) void lds_void;
typedef __attribute__((address_space(1))) void gbl_void;
#define TO_LDS(p) ((lds_void*)(uint32_t)(uintptr_t)(p))
#define TO_GBL(p) ((gbl_void*)(uintptr_t)(p))
#define ASYNC_CP16(g, l) __builtin_amdgcn_global_load_lds(TO_GBL(g), TO_LDS(l), 16, 0, 0)

__device__ __forceinline__ float bf2f(short u) {
  union { uint32_t i; float f; } x; x.i = ((uint32_t)(uint16_t)u) << 16; return x.f;
}

#define VMW_(N) asm volatile("s_waitcnt vmcnt(" #N ")" ::: "memory")
#define VMW(N) VMW_(N)
#define SB0 __builtin_amdgcn_sched_barrier(0)

// ---------------------------------------------------------------- cast f32->bf16 (batched x,wq,wk,wv)
__global__ __launch_bounds__(256) void cast4_f32_to_bf16(const float* __restrict__ s0,
                                                         const float* __restrict__ s1,
                                                         const float* __restrict__ s2,
                                                         const float* __restrict__ s3,
                                                         bf16_t* __restrict__ out) {
  const int w = blockIdx.y;
  const float* in = (w == 0) ? s0 : ((w == 1) ? s1 : ((w == 2) ? s2 : s3));
  bf16_t* o = out + (size_t)w * 16777216u;
  size_t i = (size_t)blockIdx.x * 256 + threadIdx.x;
  const f32x4* p = (const f32x4*)in + i * 2;
  f32x4 a = p[0], b = p[1];
  __align__(16) bf16_t tmp[8];
#pragma unroll
  for (int j = 0; j < 4; ++j) tmp[j]     = __float2bfloat16(a[j]);
#pragma unroll
  for (int j = 0; j < 4; ++j) tmp[4 + j] = __float2bfloat16(b[j]);
  *(short8v*)(o + i * 8) = *(const short8v*)tmp;
}

// ---------------------------------------------------------------- NT GEMM: C = A @ B^T
// 256x256 tile, BK=64, 8 waves (2M x 4N), 2-slot LDS dbuf, XOR-swizzled rows.
// Round-6/11 measured-best schedule: per phase vmcnt(4)+barrier -> ds_reads ->
// STAGE issue -> lgkm(0) -> setprio MFMA; snake quadrants, ph4 regs-only.
// Epilogues (MODE 1): z=0 plain C-write (attn reads natural layout),
// z=1 RoPE + plain-pattern C-write, z=2 V transposed [bh][d][s].
#define STAGE_A(mh_, X)                                                        \
  { const int tr_ = tid >> 3, c_ = tid & 7;                                    \
    _Pragma("unroll")                                                          \
    for (int i_ = 0; i_ < 2; ++i_) {                                           \
      const int row_ = (mh_) * 64 + i_ * 128 + tr_;                            \
      const int cg_ = c_ ^ (row_ & 7);                                         \
      ASYNC_CP16(gA0 + (size_t)row_ * 4096 + (size_t)(X) * 64 + cg_ * 8,       \
                 ldsc + (((X) & 1) << 16) + row_ * 128 + c_ * 16); } }

#define STAGE_B(nh_, X)                                                        \
  { const int tr_ = tid >> 3, c_ = tid & 7;                                    \
    _Pragma("unroll")                                                          \
    for (int i_ = 0; i_ < 2; ++i_) {                                           \
      const int row_ = i_ * 128 + (tr_ >> 5) * 64 + (nh_) * 32 + (tr_ & 31);   \
      const int cg_ = c_ ^ (row_ & 7);                                         \
      ASYNC_CP16(gB0 + (size_t)row_ * 4096 + (size_t)(X) * 64 + cg_ * 8,       \
                 ldsc + (((X) & 1) << 16) + 32768 + row_ * 128 + c_ * 16); } }

#define TILE4(T, DOSTG, VA, VB, VC)                                            \
  {                                                                            \
    const int sb = ((T) & 1) << 16;                                            \
    const int Xn = (T) + 1;                                                    \
    short8v a0[4][2], a1[4][2], b0[2][2], b1[2][2];                            \
    /* ---- ph1: (mh0,nh0) ---- */                                             \
    VMW(VA);                                                                   \
    __builtin_amdgcn_s_barrier();                                              \
    SB0;                                                                       \
    _Pragma("unroll") for (int m = 0; m < 4; ++m)                              \
      _Pragma("unroll") for (int kk = 0; kk < 2; ++kk)                         \
        a0[m][kk] = *(const short8v*)(ldsc + sb + aRow + m * 2048 + (kk ? cx1 : cx0)); \
    _Pragma("unroll") for (int n = 0; n < 2; ++n)                              \
      _Pragma("unroll") for (int kk = 0; kk < 2; ++kk)                         \
        b0[n][kk] = *(const short8v*)(ldsc + sb + bRow + n * 2048 + (kk ? cx1 : cx0)); \
    if (DOSTG) STAGE_A(0, Xn);                                                 \
    asm volatile("s_waitcnt lgkmcnt(0)" ::: "memory");                         \
    SB0;                                                                       \
    __builtin_amdgcn_s_setprio(1);                                             \
    _Pragma("unroll") for (int m = 0; m < 4; ++m)                              \
      _Pragma("unroll") for (int n = 0; n < 2; ++n)                            \
        _Pragma("unroll") for (int kk = 0; kk < 2; ++kk)                       \
          acc[m][n] = __builtin_amdgcn_mfma_f32_16x16x32_bf16(a0[m][kk], b0[n][kk], acc[m][n], 0, 0, 0); \
    __builtin_amdgcn_s_setprio(0);                                             \
    /* ---- ph2: (mh0,nh1) ---- */                                             \
    VMW(VB);                                                                   \
    __builtin_amdgcn_s_barrier();                                              \
    SB0;                                                                       \
    _Pragma("unroll") for (int n = 0; n < 2; ++n)                              \
      _Pragma("unroll") for (int kk = 0; kk < 2; ++kk)                         \
        b1[n][kk] = *(const short8v*)(ldsc + sb + bRow + 4096 + n * 2048 + (kk ? cx1 : cx0)); \
    if (DOSTG) STAGE_B(0, Xn);                                                 \
    asm volatile("s_waitcnt lgkmcnt(0)" ::: "memory");                         \
    SB0;                                                                       \
    __builtin_amdgcn_s_setprio(1);                                             \
    _Pragma("unroll") for (int m = 0; m < 4; ++m)                              \
      _Pragma("unroll") for (int n = 0; n < 2; ++n)                            \
        _Pragma("unroll") for (int kk = 0; kk < 2; ++kk)                       \
          acc[m][2 + n] = __builtin_amdgcn_mfma_f32_16x16x32_bf16(a0[m][kk], b1[n][kk], acc[m][2 + n], 0, 0, 0); \
    __builtin_amdgcn_s_setprio(0);                                             \
    /* ---- ph3: (mh1,nh1) ---- */                                             \
    VMW(VC);                                                                   \
    __builtin_amdgcn_s_barrier();                                              \
    SB0;                                                                       \
    _Pragma("unroll") for (int m = 0; m < 4; ++m)                              \
      _Pragma("unroll") for (int kk = 0; kk < 2; ++kk)                         \
        a1[m][kk] = *(const short8v*)(ldsc + sb + aRow + 8192 + m * 2048 + (kk ? cx1 : cx0)); \
    if (DOSTG) STAGE_B(1, Xn);                                                 \
    asm volatile("s_waitcnt lgkmcnt(0)" ::: "memory");                         \
    SB0;                                                                       \
    __builtin_amdgcn_s_setprio(1);                                             \
    _Pragma("unroll") for (int m = 0; m < 4; ++m)                              \
      _Pragma("unroll") for (int n = 0; n < 2; ++n)                            \
        _Pragma("unroll") for (int kk = 0; kk < 2; ++kk)                       \
          acc[4 + m][2 + n] = __builtin_amdgcn_mfma_f32_16x16x32_bf16(a1[m][kk], b1[n][kk], acc[4 + m][2 + n], 0, 0, 0); \
    __builtin_amdgcn_s_setprio(0);                                             \
    /* ---- ph4: (mh1,nh0) — regs only ---- */                                 \
    if (DOSTG) STAGE_A(1, Xn);                                                 \
    __builtin_amdgcn_s_setprio(1);                                             \
    _Pragma("unroll") for (int m = 0; m < 4; ++m)                              \
      _Pragma("unroll") for (int n = 0; n < 2; ++n)                            \
        _Pragma("unroll") for (int kk = 0; kk < 2; ++kk)                       \
          acc[4 + m][n] = __builtin_amdgcn_mfma_f32_16x16x32_bf16(a1[m][kk], b0[n][kk], acc[4 + m][n], 0, 0, 0); \
    __builtin_amdgcn_s_setprio(0);                                             \
  }

template <int MODE>   // 0: f32 C out; 1: fused qkv epilogue
__global__ __launch_bounds__(512, 2) void gemm_nt(const bf16_t* __restrict__ A,
                                                  const bf16_t* __restrict__ B0,
                                                  const bf16_t* __restrict__ B1,
                                                  const bf16_t* __restrict__ B2,
                                                  void* __restrict__ out0,
                                                  bf16_t* __restrict__ out1,
                                                  bf16_t* __restrict__ out2,
                                                  const float* __restrict__ freqs) {
  __shared__ __align__(16) char ldsbuf[131072];   // 2 slots x (A 32KB + B 32KB)
  char* ldsc = ldsbuf;
  const int z = blockIdx.z;
  const bf16_t* __restrict__ Bm = (z == 0) ? B0 : (z == 1 ? B1 : B2);
  const int tid = threadIdx.x;
  const int wave = tid >> 6, lane = tid & 63;
  // XCD swizzle: each XCD owns 2 bm x 16 bn
  const int bid = blockIdx.x;                 // 0..255
  const int xcd = bid & 7, idx = bid >> 3;    // idx 0..31
  const int bm = xcd * 2 + (idx >> 4);        // 0..15
  const int bn = idx & 15;                    // 0..15
  const int wr = wave >> 2, wc = wave & 3;    // 2 x 4 wave grid
  const int r = lane & 15, g = lane >> 4;

  f32x4 acc[8][4] = {};

  const bf16_t* gA0 = A  + (size_t)bm * 256 * 4096;
  const bf16_t* gB0 = Bm + (size_t)bn * 256 * 4096;

  // ds_read address pieces
  const int swz = r & 7;
  const int cx0 = (g ^ swz) << 4;             // kk=0 chunk byte offset
  const int cx1 = ((4 + g) ^ swz) << 4;       // kk=1
  const int aRow = (wr * 128 + r) * 128;      // + mh*8192 + m*2048
  const int bRow = 32768 + (wc * 64 + r) * 128; // + nh*4096 + n*2048

  // prologue: stage tile 0 in steady-state order
  STAGE_A(0, 0);
  STAGE_B(0, 0);
  STAGE_B(1, 0);
  STAGE_A(1, 0);

  for (int T = 0; T < 63; ++T) TILE4(T, 1, 4, 4, 4);
  TILE4(63, 0, 4, 2, 0);

  const int row0 = bm * 256 + wr * 128 + g * 4;   // + m*16 + j
  const int col0 = bn * 256 + wc * 64;            // + n*16 + r

  if (MODE == 0) {
    float* C = (float*)out0;
#pragma unroll
    for (int m = 0; m < 8; ++m)
#pragma unroll
      for (int n = 0; n < 4; ++n)
#pragma unroll
        for (int j = 0; j < 4; ++j)
          C[(size_t)(row0 + m * 16 + j) * 4096 + col0 + n * 16 + r] = acc[m][n][j];
  } else if (z == 2) {
    // V transpose: vt[(b*32+h)*128 + d][s], 4 consecutive s per 8B store
    bf16_t* VT = out2;
#pragma unroll
    for (int m = 0; m < 8; ++m) {
      const int row = row0 + m * 16;            // j = 0..3 -> s consecutive
      const int b = row >> 11, s = row & 2047;
#pragma unroll
      for (int n = 0; n < 4; ++n) {
        const int col = col0 + n * 16 + r;
        const int h = col >> 7, d = col & 127;
        __align__(8) bf16_t tp[4];
#pragma unroll
        for (int j = 0; j < 4; ++j) tp[j] = __float2bfloat16(acc[m][n][j]);
        *(short4v*)&VT[((size_t)(b * 32 + h) * 128 + d) * 2048 + s] = *(const short4v*)tp;
      }
    }
  } else if (z == 0) {
    // Q: plain coalesced C-write (natural [b][s][h][d] layout); attn reads it
    // directly with stride-4096 rows — no relayout needed.
    bf16_t* dst = (bf16_t*)out0;
#pragma unroll
    for (int m = 0; m < 8; ++m)
#pragma unroll
      for (int n = 0; n < 4; ++n)
#pragma unroll
        for (int j = 0; j < 4; ++j)
          dst[(size_t)(row0 + m * 16 + j) * 4096 + col0 + n * 16 + r] =
              __float2bfloat16(acc[m][n][j]);
  } else {
    // K: RoPE (partner in lane r^1; d-parity == lane-parity) + plain C-write
    // into natural [b][s][h][d] layout.
    bf16_t* dst = out1;
    const float sgn = (r & 1) ? 1.0f : -1.0f;
#pragma unroll
    for (int m = 0; m < 8; ++m)
#pragma unroll
      for (int j = 0; j < 4; ++j) {
        const int row = row0 + m * 16 + j;
        const int s = row & 2047;
#pragma unroll
        for (int n = 0; n < 4; ++n) {
          const int col = col0 + n * 16 + r;
          const int d = col & 127;
          const float self = acc[m][n][j];
          const float part = __shfl_xor(self, 1, 64);
          const float* fp = freqs + (size_t)s * 128 + (d >> 1) * 2;
          const float frv = fp[0];
          const float fiv = fp[1] * sgn;
          dst[(size_t)row * 4096 + col] = __float2bfloat16(self * frv + part * fiv);
        }
      }
  }
}

// ---------------------------------------------------------------- flash attention (+ wo cast side-blocks)
// Blocks 0..1023: 8 warps x 16 q-rows, 2-buffer K/V dbuf, swizzled P, Q roped
// in-register, Q/K read from natural [b][s][h][d] layout (stride-4096 rows).
// Blocks 1024..1535: cast wo f32->bf16 (overlaps attn; HBM mostly idle).
__global__ __launch_bounds__(512) void attn_kernel(const bf16_t* __restrict__ qbuf,
                                                   const bf16_t* __restrict__ kbuf,
                                                   const bf16_t* __restrict__ vt,
                                                   const float* __restrict__ freqs,
                                                   bf16_t* __restrict__ att,
                                                   const float* __restrict__ wo_src,
                                                   bf16_t* __restrict__ wo_dst) {
  __shared__ bf16_t Kls[2][64 * 128];   // 32 KB
  __shared__ bf16_t Vls[2][128 * 64];   // 32 KB
  __shared__ bf16_t Pls[8][16 * 64];    // 16 KB, XOR-swizzled

  if (blockIdx.x >= 1024) {             // wo cast: 512 blocks x 8 passes x 8 elems
    const int cb = blockIdx.x - 1024;
    const int tid = threadIdx.x;
#pragma unroll
    for (int p = 0; p < 8; ++p) {
      size_t i = ((size_t)p * 512 + cb) * 512 + tid;
      const f32x4* pp = (const f32x4*)wo_src + i * 2;
      f32x4 a = pp[0], b = pp[1];
      __align__(16) bf16_t tmp[8];
#pragma unroll
      for (int j = 0; j < 4; ++j) tmp[j]     = __float2bfloat16(a[j]);
#pragma unroll
      for (int j = 0; j < 4; ++j) tmp[4 + j] = __float2bfloat16(b[j]);
      *(short8v*)(wo_dst + i * 8) = *(const short8v*)tmp;
    }
    return;
  }

  const int lid  = blockIdx.x;             // 0..1023
  const int xcd  = lid & 7;
  const int kk_  = lid >> 3;               // 0..127
  const int bh   = xcd + 8 * ((kk_ >> 4) & 7);
  const int qidx = 15 - (kk_ & 15);        // longest blocks dispatched first
  const int warp = threadIdx.x >> 6;
  const int lane = threadIdx.x & 63;
  const int r = lane & 15, g = lane >> 4;

  const int bb = bh >> 5, hh = bh & 31;
  const bf16_t* __restrict__ Q  = qbuf + (size_t)bb * 2048 * 4096 + hh * 128;
  const bf16_t* __restrict__ Kp = kbuf + (size_t)bb * 2048 * 4096 + hh * 128;
  const bf16_t* __restrict__ Vt = vt   + (size_t)bh * 128 * 2048;
  char* __restrict__ Pb = (char*)&Pls[warp][0];

  const int qB = qidx * 128 + warp * 16;
  const int ntiles = 2 * qidx + 2;
  const int psw = (r & 7) << 4;            // P swizzle

  // Q fragments: load raw (stride-4096 rows), RoPE + RSCALE in-register.
  short8v qf[4];
  {
    const int s = qB + r;
    const float* fbase = freqs + (size_t)s * 128;
#pragma unroll
    for (int kk = 0; kk < 4; ++kk) {
      short8v qraw = *(const short8v*)&Q[(size_t)s * 4096 + kk * 32 + g * 8];
      __align__(16) bf16_t qt[8];
#pragma unroll
      for (int i = 0; i < 4; ++i) {
        const int p = kk * 16 + g * 4 + i;
        f32x2 cs = *(const f32x2*)(fbase + p * 2);
        const float a = bf2f(qraw[2 * i]), b = bf2f(qraw[2 * i + 1]);
        qt[2 * i]     = __float2bfloat16((a * cs[0] - b * cs[1]) * RSCALE);
        qt[2 * i + 1] = __float2bfloat16((a * cs[1] + b * cs[0]) * RSCALE);
      }
      qf[kk] = *(const short8v*)qt;
    }
  }

  float l = 0.f;
  f32x4 o[8];
#pragma unroll
  for (int n2 = 0; n2 < 8; ++n2) o[n2] = f32x4{0.f, 0.f, 0.f, 0.f};

  const int rA = lane >> 4, cA = lane & 15;
  const int rB = lane >> 3, cB = lane & 7;
  const int swz = (r & 7) << 4;

  auto STG = [&](int kb_, int buf) {
#pragma unroll
    for (int i = 0; i < 2; ++i) {
      const int krow = warp * 8 + i * 4 + rA;
      const int kcol = 8 * (cA ^ (krow & 7));
      ASYNC_CP16(Kp + (size_t)(kb_ + krow) * 4096 + kcol,
                 (char*)&Kls[buf][0] + (size_t)(krow * 128 + cA * 8) * 2);
    }
#pragma unroll
    for (int i = 0; i < 2; ++i) {
      const int vrow = warp * 16 + i * 8 + rB;
      const int vcol = 8 * (cB ^ rB);
      ASYNC_CP16(Vt + (size_t)vrow * 2048 + kb_ + vcol,
                 (char*)&Vls[buf][0] + (size_t)(vrow * 64 + cB * 8) * 2);
    }
  };

  STG(0, 0);
  VMW(0);
  __builtin_amdgcn_s_barrier();
  int cur = 0;
  for (int t = 0; t < ntiles; ++t) {
    const int kb = t * 64;
    if (t + 1 < ntiles) STG(kb + 64, cur ^ 1);

    if (kb <= qB + 15) {
      const char* Kc = (const char*)&Kls[cur][0];
      const char* Vc = (const char*)&Vls[cur][0];
      f32x4 sacc[4];
#pragma unroll
      for (int n = 0; n < 4; ++n) sacc[n] = f32x4{0.f, 0.f, 0.f, 0.f};
      __builtin_amdgcn_s_setprio(1);
#pragma unroll
      for (int n = 0; n < 4; ++n)
#pragma unroll
        for (int kk = 0; kk < 4; ++kk) {
          short8v kf = *(const short8v*)(Kc + (n * 16 + r) * 256 + ((kk * 64 + g * 16) ^ swz));
          sacc[n] = __builtin_amdgcn_mfma_f32_16x16x32_bf16(kf, qf[kk], sacc[n], 0, 0, 0);
        }
      __builtin_amdgcn_s_setprio(0);

      float p[16];
#pragma unroll
      for (int n = 0; n < 4; ++n)
#pragma unroll
        for (int j = 0; j < 4; ++j)
          p[n * 4 + j] = __expf(sacc[n][j]);

      if (kb + 63 > qB) {
        const int qa = qB + r;
#pragma unroll
        for (int n = 0; n < 4; ++n)
#pragma unroll
          for (int j = 0; j < 4; ++j)
            if (kb + n * 16 + g * 4 + j > qa) p[n * 4 + j] = 0.f;
      }

      {
        float ts[8];
#pragma unroll
        for (int i = 0; i < 8; ++i) ts[i] = p[i] + p[i + 8];
#pragma unroll
        for (int i = 0; i < 4; ++i) ts[i] += ts[i + 4];
        float rs = (ts[0] + ts[1]) + (ts[2] + ts[3]);
        rs += __shfl_xor(rs, 16, 64);
        rs += __shfl_xor(rs, 32, 64);
        l += rs;
      }

      // stage P, swizzled: raw byte = r*128 + n*32 + g*8, XOR (r&7)<<4
#pragma unroll
      for (int n = 0; n < 4; ++n) {
        __align__(8) bf16_t tp[4];
#pragma unroll
        for (int j = 0; j < 4; ++j) tp[j] = __float2bfloat16(p[n * 4 + j]);
        *(short4v*)(Pb + r * 128 + ((n * 32 + g * 8) ^ psw)) = *(const short4v*)tp;
      }

      __builtin_amdgcn_s_setprio(1);
#pragma unroll
      for (int kk2 = 0; kk2 < 2; ++kk2) {
        short8v pf = *(const short8v*)(Pb + r * 128 + ((kk2 * 64 + g * 16) ^ psw));
#pragma unroll
        for (int n2 = 0; n2 < 8; ++n2) {
          short8v vf = *(const short8v*)(Vc + (n2 * 16 + r) * 128 + ((kk2 * 64 + g * 16) ^ swz));
          o[n2] = __builtin_amdgcn_mfma_f32_16x16x32_bf16(pf, vf, o[n2], 0, 0, 0);
        }
      }
      __builtin_amdgcn_s_setprio(0);
    }

    if (t + 1 < ntiles) {
      VMW(0);                       // my t+1 loads landed during compute(t)
      __builtin_amdgcn_s_barrier(); // publish all warps' loads; WAR fence
    }
    cur ^= 1;
  }

  float lq[4];
#pragma unroll
  for (int j = 0; j < 4; ++j) lq[j] = 1.0f / __shfl(l, g * 4 + j, 64);
#pragma unroll
  for (int n2 = 0; n2 < 8; ++n2)
#pragma unroll
    for (int j = 0; j < 4; ++j)
      att[((size_t)(bb * 2048 + qB + g * 4 + j)) * 4096 + hh * 128 + n2 * 16 + r] =
          __float2bfloat16(o[n2][j] * lq[j]);
}

// ---------------------------------------------------------------- launch
extern "C" void kernel_launch(void* const* d_in, const int* in_sizes, int n_in,
                              void* d_out, int out_size, void* d_ws, size_t ws_size,
                              hipStream_t stream) {
  (void)in_sizes; (void)n_in; (void)out_size; (void)ws_size;
  const float* x  = (const float*)d_in[0];
  const float* fr = (const float*)d_in[1];
  const float* wq = (const float*)d_in[3];
  const float* wk = (const float*)d_in[4];
  const float* wv = (const float*)d_in[5];
  const float* wo = (const float*)d_in[6];

  char* ws = (char*)d_ws;
  const size_t MB32 = 33554432;
  bf16_t* xb   = (bf16_t*)(ws + 0 * MB32);   // later: attb
  bf16_t* wqb  = (bf16_t*)(ws + 1 * MB32);   // later: wob
  bf16_t* wkb  = (bf16_t*)(ws + 2 * MB32);
  bf16_t* wvb  = (bf16_t*)(ws + 3 * MB32);
  bf16_t* qbuf = (bf16_t*)(ws + 4 * MB32);   // Q, natural [b][s][h][d]
  bf16_t* kbuf = (bf16_t*)(ws + 5 * MB32);   // K roped, natural layout
  bf16_t* vtp  = (bf16_t*)(ws + 6 * MB32);   // V^T [bh][d][s]

  cast4_f32_to_bf16<<<dim3(8192, 4), 256, 0, stream>>>(x, wq, wk, wv, xb);

  // qkv projections; z=0 plain, z=1 rope, z=2 transpose
  gemm_nt<1><<<dim3(256, 1, 3), 512, 0, stream>>>(xb, wqb, wkb, wvb,
                                                  (void*)qbuf, kbuf, vtp, fr);

  bf16_t* wob  = wqb;
  bf16_t* attb = xb;

  // attn + concurrent wo cast (blocks >= 1024)
  attn_kernel<<<1536, 512, 0, stream>>>(qbuf, kbuf, vtp, fr, attb, wo, wob);

  gemm_nt<0><<<dim3(256, 1, 1), 512, 0, stream>>>(attb, wob, wob, wob,
                                                  d_out, nullptr, nullptr, nullptr);
}